// Round 14
// baseline (59.011 us; speedup 1.0000x reference)
//
#include <hip/hip_runtime.h>
#include <stdint.h>

// Sizes (fixed by the problem)
#define NCAP 64
#define NIMG 64
#define LTOK 64
#define RREG 36
#define EDIM 512
#define LAM 9.0f
#define SSTR 38  // S-exchange row stride (floats)

// imgT per-image layout (shorts): 32 full frags (n=0,1; 512 shorts each) at
// 0..16383, then 16 quarter-frags (n=2 rows 32..35; 128 shorts each) at
// 16384..18431. Per-image stride 18432 shorts = 36864 B.
#define IMGT_STRIDE 18432

// k_main: K-split occupancy build. Chunk = 26KB (A 8KB + B 16KB + Q 2KB),
// single-buffered; LDS = S [4][64][38] f32 (38912) + 8 partial floats
// = 38976 B -> 4 blocks/CU; grid 1024 blocks -> 32 waves/CU target.
#define CHUNK_BYTES 26624
#define LDS_BYTES 38976

typedef __attribute__((ext_vector_type(8))) short bf16x8;
typedef __attribute__((ext_vector_type(4))) float f32x4;
typedef __attribute__((ext_vector_type(8))) unsigned short u16x8;

typedef const __attribute__((address_space(1))) void* gas1_t;
typedef __attribute__((address_space(3))) void* las3_t;

__device__ __forceinline__ void gl16(const void* g, void* l) {
  // stages 16B/lane: LDS dest = l + lane*16 (wave-uniform base), global src
  // is per-lane.
  __builtin_amdgcn_global_load_lds((gas1_t)g, (las3_t)l, 16, 0, 0);
}

__device__ __forceinline__ unsigned short f2bf(float f) {
  unsigned int u = __float_as_uint(f);
  u += 0x7FFFu + ((u >> 16) & 1u);  // RNE
  return (unsigned short)(u >> 16);
}

// Fused prep kernel, 1664 blocks (UNCHANGED from round 10):
//   blocks 0..63 (dispatched FIRST): per-image MFMA gram.
//   blocks 64..1663: L2-normalize 6400 rows into capT/imgT frag layouts.
__global__ __launch_bounds__(256) void k_prep(const float* __restrict__ cap,
                                              const float* __restrict__ img,
                                              unsigned short* __restrict__ capT,
                                              unsigned short* __restrict__ imgT,
                                              float* __restrict__ G2) {
  __shared__ __align__(16) char gfr[49152];  // 3 tiles x 16 kk x 1024B
  int tid = threadIdx.x;
  int w = tid >> 6, lane = tid & 63;
  int bid = blockIdx.x;

  if (bid < 64) {
    // ---- MFMA gram for image i = bid ----
    int i = bid;
    // zero the pad slots of tile 2 (frag slots with r15 >= 4)
    for (int t = tid; t < 1024; t += 256) {
      if ((t & 15) >= 4) {
        u16x8 z = {};
        *(u16x8*)(gfr + 32768 + t * 16) = z;
      }
    }
    // normalize rows -> LDS frag scatter (wave w does rows w, w+4, ...)
    int kk = lane >> 2, kg = lane & 3;
#pragma unroll
    for (int t = 0; t < 9; ++t) {
      int r = w + t * 4;  // 0..35
      const float* p = img + ((size_t)i * RREG + r) * EDIM + lane * 8;
      float4 a = *(const float4*)p;
      float4 b = *(const float4*)(p + 4);
      float ss = a.x * a.x + a.y * a.y + a.z * a.z + a.w * a.w +
                 b.x * b.x + b.y * b.y + b.z * b.z + b.w * b.w;
#pragma unroll
      for (int off = 1; off < 64; off <<= 1) ss += __shfl_xor(ss, off);
      float sc = 1.0f / fmaxf(sqrtf(ss), 1e-12f);
      u16x8 o = {f2bf(a.x * sc), f2bf(a.y * sc), f2bf(a.z * sc),
                 f2bf(a.w * sc), f2bf(b.x * sc), f2bf(b.y * sc),
                 f2bf(b.z * sc), f2bf(b.w * sc)};
      *(u16x8*)(gfr + (r >> 4) * 16384 + kk * 1024 +
                ((kg << 4) + (r & 15)) * 16) = o;
    }
    __syncthreads();
    if (w < 3) {  // wave w = row-tile mi; 3 col-tiles each
      f32x4 acc3[3];
#pragma unroll
      for (int n = 0; n < 3; ++n) acc3[n] = 0.f;
#pragma unroll
      for (int k2 = 0; k2 < 16; ++k2) {
        bf16x8 av = *(const bf16x8*)(gfr + w * 16384 + k2 * 1024 + lane * 16);
        bf16x8 b0 = *(const bf16x8*)(gfr + 0 * 16384 + k2 * 1024 + lane * 16);
        bf16x8 b1 = *(const bf16x8*)(gfr + 1 * 16384 + k2 * 1024 + lane * 16);
        bf16x8 b2 = *(const bf16x8*)(gfr + 2 * 16384 + k2 * 1024 + lane * 16);
        acc3[0] = __builtin_amdgcn_mfma_f32_16x16x32_bf16(av, b0, acc3[0], 0, 0, 0);
        acc3[1] = __builtin_amdgcn_mfma_f32_16x16x32_bf16(av, b1, acc3[1], 0, 0, 0);
        acc3[2] = __builtin_amdgcn_mfma_f32_16x16x32_bf16(av, b2, acc3[2], 0, 0, 0);
      }
      int rq = lane & 15, kgq = lane >> 4;
#pragma unroll
      for (int n = 0; n < 3; ++n)
#pragma unroll
        for (int j = 0; j < 4; ++j) {
          int R = w * 16 + kgq * 4 + j, C = n * 16 + rq;
          if (R < RREG && C < RREG) {
            float v = acc3[n][j];
            G2[(size_t)i * 1296 + R * 36 + C] = (R == C) ? v : 2.0f * v;
          }
        }
    }
    return;
  }

  // ---- norm + fragment scatter ----
  int kkw = lane >> 2, kgw = lane & 3;  // lane's (kk, kg) in frag layout
  int v = (bid - 64) * 4 + w;
  const float* p;
  unsigned short* dst;
  if (v < NCAP * LTOK) {
    int c = v >> 6, row = v & 63;
    int m = row >> 4, rqw = row & 15;
    p = cap + (size_t)v * EDIM + lane * 8;
    dst = capT + (size_t)c * 32768 +
          (size_t)(((m * 16 + kkw) * 64 + kgw * 16 + rqw) * 8);
  } else {
    int vi = v - NCAP * LTOK;
    int i = vi / RREG;
    int r = vi - i * RREG;
    p = img + ((size_t)i * RREG + r) * EDIM + lane * 8;
    if (r < 32) {
      int n = r >> 4, rqw = r & 15;
      dst = imgT + (size_t)i * IMGT_STRIDE +
            (size_t)(((n * 16 + kkw) * 64 + kgw * 16 + rqw) * 8);
    } else {
      int rq2 = r - 32;  // 0..3
      dst = imgT + (size_t)i * IMGT_STRIDE + 16384 +
            (size_t)(kkw * 128 + (kgw * 4 + rq2) * 8);
    }
  }
  float4 a = *(const float4*)p;
  float4 b = *(const float4*)(p + 4);
  float ss = a.x * a.x + a.y * a.y + a.z * a.z + a.w * a.w +
             b.x * b.x + b.y * b.y + b.z * b.z + b.w * b.w;
#pragma unroll
  for (int off = 1; off < 64; off <<= 1) ss += __shfl_xor(ss, off);
  float sc = 1.0f / fmaxf(sqrtf(ss), 1e-12f);
  u16x8 o = {f2bf(a.x * sc), f2bf(a.y * sc), f2bf(a.z * sc), f2bf(a.w * sc),
             f2bf(b.x * sc), f2bf(b.y * sc), f2bf(b.z * sc), f2bf(b.w * sc)};
  *(u16x8*)dst = o;
}

// Stage one K-split chunk (1 caption + 4 images, kk = ch for kh0 and 8+ch
// for kh1) into LDS buf. 26 gl16 ops over 8 waves (waves 0,1: 4; rest: 3).
// Layout (bytes): A [m][kh] at (m*2+kh)*1024; B [kh][img][n] at
// 8192 + (kh*8+img*2+n)*1024; Q [kh] at 24576 + kh*1024 (img subslots).
__device__ __forceinline__ void stage_chunk(const unsigned short* capT,
                                            const unsigned short* imgT,
                                            char* buf, int c, int i0, int ch,
                                            int w, int lane) {
#pragma unroll
  for (int j = 0; j < 4; ++j) {
    int t = w + j * 8;
    if (t < 8) {
      int m = t >> 1, khs = t & 1;
      const unsigned short* src =
          capT + (size_t)c * 32768 +
          (size_t)((m * 16 + khs * 8 + ch) * 512) + lane * 8;
      gl16(src, buf + t * 1024);
    } else if (t < 24) {
      int u = t - 8;
      int khs = u >> 3, img = (u >> 1) & 3, n = u & 1;
      const unsigned short* src =
          imgT + (size_t)(i0 + img) * IMGT_STRIDE +
          (size_t)((n * 16 + khs * 8 + ch) * 512) + lane * 8;
      gl16(src, buf + 8192 + u * 1024);
    } else if (t < 26) {
      int khs = t - 24;
      const unsigned short* src =
          imgT + (size_t)(i0 + (lane >> 4)) * IMGT_STRIDE + 16384 +
          (khs * 8 + ch) * 128 + (lane & 15) * 8;
      gl16(src, buf + 24576 + khs * 1024);
    }
  }
}

// ---------------- main fused kernel (K-SPLIT OCCUPANCY BUILD) -----------
// Block = (1 caption, 4 images), 8 waves: wave (wi = w&3, kh = w>>2)
// computes the kh-th K-half (256 cols) of pair (c, i0+wi). Grid 1024
// blocks; LDS 38976 B -> 4 blocks/CU -> 32 waves/CU. Single-buffered
// 26KB chunk staging (co-resident blocks hide the latency). S-combine:
// kh0 writes, kh1 adds; epilogue on lanes 0..31 per wave (32 tokens).
__global__ __launch_bounds__(512, 4) void k_main(
    const unsigned short* __restrict__ capT,
    const unsigned short* __restrict__ imgT, const float* __restrict__ G2,
    const int* __restrict__ lens, float* __restrict__ out) {
  __shared__ __align__(16) char lds[LDS_BYTES];
  int tid = threadIdx.x;
  int w = tid >> 6, lane = tid & 63;
  int wi = w & 3, kh = w >> 2;
  int rq = lane & 15, kg = lane >> 4;
  int bid = blockIdx.x;
  int b = (bid & 7) * 128 + (bid >> 3);  // XCD swizzle (1024 % 8 == 0)
  int c = b >> 4;
  int i0 = (b & 15) * 4;

  f32x4 acc[4][3];
#pragma unroll
  for (int m = 0; m < 4; ++m)
#pragma unroll
    for (int n = 0; n < 3; ++n) acc[m][n] = 0.f;

  int aoff = kh * 1024 + lane * 16;
  int boff = 8192 + (kh * 8 + wi * 2) * 1024 + lane * 16;
  int qoff = 24576 + kh * 1024 + wi * 256 + (kg * 4 + (rq & 3)) * 16;

  stage_chunk(capT, imgT, lds, c, i0, 0, w, lane);
  __syncthreads();
#pragma unroll
  for (int ch = 0; ch < 8; ++ch) {
    bf16x8 a0 = *(const bf16x8*)(lds + aoff + 0 * 2048);
    bf16x8 a1 = *(const bf16x8*)(lds + aoff + 1 * 2048);
    bf16x8 a2 = *(const bf16x8*)(lds + aoff + 2 * 2048);
    bf16x8 a3 = *(const bf16x8*)(lds + aoff + 3 * 2048);
    bf16x8 b0 = *(const bf16x8*)(lds + boff + 0 * 1024);
    bf16x8 b1 = *(const bf16x8*)(lds + boff + 1 * 1024);
    // quarter frag: cols 32..35; lanes rq>=4 read duplicate data whose
    // MFMA output cols (36..47) are never stored -> no masking needed.
    bf16x8 b2 = *(const bf16x8*)(lds + qoff);

    acc[0][0] = __builtin_amdgcn_mfma_f32_16x16x32_bf16(a0, b0, acc[0][0], 0, 0, 0);
    acc[0][1] = __builtin_amdgcn_mfma_f32_16x16x32_bf16(a0, b1, acc[0][1], 0, 0, 0);
    acc[0][2] = __builtin_amdgcn_mfma_f32_16x16x32_bf16(a0, b2, acc[0][2], 0, 0, 0);
    acc[1][0] = __builtin_amdgcn_mfma_f32_16x16x32_bf16(a1, b0, acc[1][0], 0, 0, 0);
    acc[1][1] = __builtin_amdgcn_mfma_f32_16x16x32_bf16(a1, b1, acc[1][1], 0, 0, 0);
    acc[1][2] = __builtin_amdgcn_mfma_f32_16x16x32_bf16(a1, b2, acc[1][2], 0, 0, 0);
    acc[2][0] = __builtin_amdgcn_mfma_f32_16x16x32_bf16(a2, b0, acc[2][0], 0, 0, 0);
    acc[2][1] = __builtin_amdgcn_mfma_f32_16x16x32_bf16(a2, b1, acc[2][1], 0, 0, 0);
    acc[2][2] = __builtin_amdgcn_mfma_f32_16x16x32_bf16(a2, b2, acc[2][2], 0, 0, 0);
    acc[3][0] = __builtin_amdgcn_mfma_f32_16x16x32_bf16(a3, b0, acc[3][0], 0, 0, 0);
    acc[3][1] = __builtin_amdgcn_mfma_f32_16x16x32_bf16(a3, b1, acc[3][1], 0, 0, 0);
    acc[3][2] = __builtin_amdgcn_mfma_f32_16x16x32_bf16(a3, b2, acc[3][2], 0, 0, 0);

    __syncthreads();  // all waves done reading buf
    if (ch < 7) {
      stage_chunk(capT, imgT, lds, c, i0, ch + 1, w, lane);
      __syncthreads();  // implies vmcnt(0): staged data visible to all
    }
  }

  // ---- K-half combine + epilogue ----
  // D layout: col = lane&15, row = (lane>>4)*4 + j.
  float* Sf = (float*)lds;
  float* part = (float*)(lds + 38912);  // 8 floats
  int i = i0 + wi;
  int iu = __builtin_amdgcn_readfirstlane(i);
  const float* Gi = G2 + (size_t)iu * 1296;
  int len = lens[c];

  if (kh == 0) {
#pragma unroll
    for (int m = 0; m < 4; ++m)
#pragma unroll
      for (int n = 0; n < 3; ++n)
#pragma unroll
        for (int j = 0; j < 4; ++j)
          if (n < 2 || rq < 4)
            Sf[(wi * 64 + m * 16 + kg * 4 + j) * SSTR + n * 16 + rq] =
                acc[m][n][j];
  }
  __syncthreads();
  if (kh == 1) {
#pragma unroll
    for (int m = 0; m < 4; ++m)
#pragma unroll
      for (int n = 0; n < 3; ++n)
#pragma unroll
        for (int j = 0; j < 4; ++j)
          if (n < 2 || rq < 4) {
            int idx = (wi * 64 + m * 16 + kg * 4 + j) * SSTR + n * 16 + rq;
            Sf[idx] += acc[m][n][j];
          }
  }
  __syncthreads();

  // wave (wi,kh): tokens kh*32 + 0..31 of pair (c, i0+wi); lanes 0..31.
  if (lane < 32) {
    int tok = kh * 32 + lane;
    const float* Srow = Sf + (size_t)(wi * 64 + tok) * SSTR;
    float s[36];
#pragma unroll
    for (int r2 = 0; r2 < 18; ++r2) {
      float2 x = *(const float2*)(Srow + r2 * 2);
      s[r2 * 2 + 0] = x.x;
      s[r2 * 2 + 1] = x.y;
    }
    float mx = s[0];
#pragma unroll
    for (int r = 1; r < 36; ++r) mx = fmaxf(mx, s[r]);
    float p[36];
    float sum = 0.f, dotp = 0.f;
#pragma unroll
    for (int r = 0; r < 36; ++r) {
      p[r] = __expf(LAM * (s[r] - mx));
      sum += p[r];
      dotp = fmaf(p[r], s[r], dotp);
    }
    // q2 = p^T G p via triangular loop (G2 has off-diag pre-doubled)
    float q2 = 0.f;
#pragma unroll
    for (int r2 = 0; r2 < 36; ++r2) {
      float t = 0.f;
#pragma unroll
      for (int r = 0; r <= r2; ++r) t = fmaf(Gi[r2 * 36 + r], p[r], t);
      q2 = fmaf(t, p[r2], q2);
    }
    float inv = 1.0f / sum;
    float dn = dotp * inv;
    float nb = sqrtf(fmaxf(q2, 0.f)) * inv;
    float rcos = dn / fmaxf(nb, 1e-8f);
    float val = (tok < len) ? rcos : 0.f;
    // 32-lane reduce (offsets <= 16 stay within lanes 0..31, all active)
#pragma unroll
    for (int off = 1; off < 32; off <<= 1) val += __shfl_xor(val, off);
    if (lane == 0) part[wi * 2 + kh] = val;
  }
  __syncthreads();
  if (tid < 4)
    out[c * 64 + i0 + tid] = (part[tid * 2] + part[tid * 2 + 1]) * (1.0f / 64.0f);
}

extern "C" void kernel_launch(void* const* d_in, const int* in_sizes, int n_in,
                              void* d_out, int out_size, void* d_ws,
                              size_t ws_size, hipStream_t stream) {
  const float* images = (const float*)d_in[0];    // (64,36,512) f32
  const float* captions = (const float*)d_in[1];  // (64,64,512) f32
  const int* lens = (const int*)d_in[2];          // (64,)
  float* out = (float*)d_out;                     // (64,64) f32

  char* ws = (char*)d_ws;
  unsigned short* capT = (unsigned short*)ws;              // 4096*512*2 = 4 MB
  unsigned short* imgT = (unsigned short*)(ws + 4194304);  // 64*18432*2
  float* G = (float*)(ws + 4194304 + 2359296);             // 64*1296*4

  k_prep<<<1664, 256, 0, stream>>>(captions, images, capT, imgT, G);
  k_main<<<1024, 512, 0, stream>>>(capT, imgT, G, lens, out);
}

// Round 15
// 38.303 us; speedup vs baseline: 1.5406x; 1.5406x over previous
//
#include <hip/hip_runtime.h>
#include <stdint.h>

// Sizes (fixed by the problem)
#define NCAP 64
#define NIMG 64
#define LTOK 64
#define RREG 36
#define EDIM 512
#define LAM 9.0f
#define SSTR 38  // S-exchange row stride (floats)

// imgT per-image layout (shorts): 32 full frags (n=0,1; 512 shorts each) at
// 0..16383, then 16 quarter-frags (n=2 rows 32..35; 128 shorts each) at
// 16384..18431. Per-image stride 18432 shorts = 36864 B.
#define IMGT_STRIDE 18432

// k_main chunk staging: A 16KB + B-full 16KB + B-quarter 2KB = 34KB
#define CHUNK_BYTES 34816
#define LDS_BYTES 77824  // = 8 pairs * 64 tok * 38 f32 (S) >= 2*CHUNK_BYTES

typedef __attribute__((ext_vector_type(8))) short bf16x8;
typedef __attribute__((ext_vector_type(4))) float f32x4;
typedef __attribute__((ext_vector_type(8))) unsigned short u16x8;

typedef const __attribute__((address_space(1))) void* gas1_t;
typedef __attribute__((address_space(3))) void* las3_t;

__device__ __forceinline__ void gl16(const void* g, void* l) {
  // stages 16B/lane: LDS dest = l + lane*16 (wave-uniform base), global src
  // is per-lane.
  __builtin_amdgcn_global_load_lds((gas1_t)g, (las3_t)l, 16, 0, 0);
}

__device__ __forceinline__ unsigned short f2bf(float f) {
  unsigned int u = __float_as_uint(f);
  u += 0x7FFFu + ((u >> 16) & 1u);  // RNE
  return (unsigned short)(u >> 16);
}

// Fused prep kernel, 1664 blocks:
//   blocks 0..63 (dispatched FIRST): per-image MFMA gram. Self-normalizes
//     the image's 36 rows (identical math to the norm path), scatters bf16
//     frags into LDS (pad rows zeroed), then 3 waves x 48 MFMAs compute
//     G = V V^T; stores normalized entries with off-diagonal pre-doubled.
//   blocks 64..1663: L2-normalize 6400 rows (4096 cap + 2304 img) into the
//     global MFMA fragment layouts capT/imgT (1 row per wave).
__global__ __launch_bounds__(256) void k_prep(const float* __restrict__ cap,
                                              const float* __restrict__ img,
                                              unsigned short* __restrict__ capT,
                                              unsigned short* __restrict__ imgT,
                                              float* __restrict__ G2) {
  __shared__ __align__(16) char gfr[49152];  // 3 tiles x 16 kk x 1024B
  int tid = threadIdx.x;
  int w = tid >> 6, lane = tid & 63;
  int bid = blockIdx.x;

  if (bid < 64) {
    // ---- MFMA gram for image i = bid ----
    int i = bid;
    // zero the pad slots of tile 2 (frag slots with r15 >= 4)
    for (int t = tid; t < 1024; t += 256) {
      if ((t & 15) >= 4) {
        u16x8 z = {};
        *(u16x8*)(gfr + 32768 + t * 16) = z;
      }
    }
    // normalize rows -> LDS frag scatter (wave w does rows w, w+4, ...)
    int kk = lane >> 2, kg = lane & 3;
#pragma unroll
    for (int t = 0; t < 9; ++t) {
      int r = w + t * 4;  // 0..35
      const float* p = img + ((size_t)i * RREG + r) * EDIM + lane * 8;
      float4 a = *(const float4*)p;
      float4 b = *(const float4*)(p + 4);
      float ss = a.x * a.x + a.y * a.y + a.z * a.z + a.w * a.w +
                 b.x * b.x + b.y * b.y + b.z * b.z + b.w * b.w;
#pragma unroll
      for (int off = 1; off < 64; off <<= 1) ss += __shfl_xor(ss, off);
      float sc = 1.0f / fmaxf(sqrtf(ss), 1e-12f);
      u16x8 o = {f2bf(a.x * sc), f2bf(a.y * sc), f2bf(a.z * sc),
                 f2bf(a.w * sc), f2bf(b.x * sc), f2bf(b.y * sc),
                 f2bf(b.z * sc), f2bf(b.w * sc)};
      *(u16x8*)(gfr + (r >> 4) * 16384 + kk * 1024 +
                ((kg << 4) + (r & 15)) * 16) = o;
    }
    __syncthreads();
    if (w < 3) {  // wave w = row-tile mi; 3 col-tiles each
      f32x4 acc3[3];
#pragma unroll
      for (int n = 0; n < 3; ++n) acc3[n] = 0.f;
#pragma unroll
      for (int k2 = 0; k2 < 16; ++k2) {
        bf16x8 av = *(const bf16x8*)(gfr + w * 16384 + k2 * 1024 + lane * 16);
        bf16x8 b0 = *(const bf16x8*)(gfr + 0 * 16384 + k2 * 1024 + lane * 16);
        bf16x8 b1 = *(const bf16x8*)(gfr + 1 * 16384 + k2 * 1024 + lane * 16);
        bf16x8 b2 = *(const bf16x8*)(gfr + 2 * 16384 + k2 * 1024 + lane * 16);
        acc3[0] = __builtin_amdgcn_mfma_f32_16x16x32_bf16(av, b0, acc3[0], 0, 0, 0);
        acc3[1] = __builtin_amdgcn_mfma_f32_16x16x32_bf16(av, b1, acc3[1], 0, 0, 0);
        acc3[2] = __builtin_amdgcn_mfma_f32_16x16x32_bf16(av, b2, acc3[2], 0, 0, 0);
      }
      int rq = lane & 15, kgq = lane >> 4;
#pragma unroll
      for (int n = 0; n < 3; ++n)
#pragma unroll
        for (int j = 0; j < 4; ++j) {
          int R = w * 16 + kgq * 4 + j, C = n * 16 + rq;
          if (R < RREG && C < RREG) {
            float v = acc3[n][j];
            G2[(size_t)i * 1296 + R * 36 + C] = (R == C) ? v : 2.0f * v;
          }
        }
    }
    return;
  }

  // ---- norm + fragment scatter ----
  int kkw = lane >> 2, kgw = lane & 3;  // lane's (kk, kg) in frag layout
  int v = (bid - 64) * 4 + w;
  const float* p;
  unsigned short* dst;
  if (v < NCAP * LTOK) {
    int c = v >> 6, row = v & 63;
    int m = row >> 4, rqw = row & 15;
    p = cap + (size_t)v * EDIM + lane * 8;
    dst = capT + (size_t)c * 32768 +
          (size_t)(((m * 16 + kkw) * 64 + kgw * 16 + rqw) * 8);
  } else {
    int vi = v - NCAP * LTOK;
    int i = vi / RREG;
    int r = vi - i * RREG;
    p = img + ((size_t)i * RREG + r) * EDIM + lane * 8;
    if (r < 32) {
      int n = r >> 4, rqw = r & 15;
      dst = imgT + (size_t)i * IMGT_STRIDE +
            (size_t)(((n * 16 + kkw) * 64 + kgw * 16 + rqw) * 8);
    } else {
      int rq2 = r - 32;  // 0..3
      dst = imgT + (size_t)i * IMGT_STRIDE + 16384 +
            (size_t)(kkw * 128 + (kgw * 4 + rq2) * 8);
    }
  }
  float4 a = *(const float4*)p;
  float4 b = *(const float4*)(p + 4);
  float ss = a.x * a.x + a.y * a.y + a.z * a.z + a.w * a.w +
             b.x * b.x + b.y * b.y + b.z * b.z + b.w * b.w;
#pragma unroll
  for (int off = 1; off < 64; off <<= 1) ss += __shfl_xor(ss, off);
  float sc = 1.0f / fmaxf(sqrtf(ss), 1e-12f);
  u16x8 o = {f2bf(a.x * sc), f2bf(a.y * sc), f2bf(a.z * sc), f2bf(a.w * sc),
             f2bf(b.x * sc), f2bf(b.y * sc), f2bf(b.z * sc), f2bf(b.w * sc)};
  *(u16x8*)dst = o;
}

// Stage one 64-col K-chunk for 2 captions + 4 images into LDS buf.
// 34 gl16 ops split across 8 waves; waves 0,1 issue 5, waves 2..7 issue 4.
__device__ __forceinline__ void stage_chunk(const unsigned short* capT,
                                            const unsigned short* imgT,
                                            char* buf, int c0, int i0, int ch,
                                            int w, int lane) {
#pragma unroll
  for (int j = 0; j < 5; ++j) {
    int t = w + j * 8;
    if (t < 16) {
      // A frag: t = wcap*8 + m*2 + kk
      int wcap = t >> 3, m = (t >> 1) & 3, kk = t & 1;
      const unsigned short* src =
          capT + (size_t)(c0 + wcap) * 32768 +
          (size_t)((m * 16 + ch * 2 + kk) * 512) + lane * 8;
      gl16(src, buf + (wcap * 8 + m * 2 + kk) * 1024);
    } else if (t < 32) {
      // B full frag: u = kk*8 + i*2 + f
      int u = t - 16;
      int kk = u >> 3, i = (u >> 1) & 3, f = u & 1;
      const unsigned short* src =
          imgT + (size_t)(i0 + i) * IMGT_STRIDE +
          (size_t)((f * 16 + ch * 2 + kk) * 512) + lane * 8;
      gl16(src, buf + 16384 + ((kk * 4 + i) * 2 + f) * 1024);
    } else if (t < 34) {
      // combined quarter frag (4 images, per-lane scattered source)
      int kk = t - 32;
      const unsigned short* src =
          imgT + (size_t)(i0 + (lane >> 4)) * IMGT_STRIDE + 16384 +
          (ch * 2 + kk) * 128 + (lane & 15) * 8;
      gl16(src, buf + 32768 + kk * 1024);
    }
  }
}

// ---------------- main fused kernel (restored round-10/11 optimum) -------
// Block = (2 captions, 4 images), 8 waves; double-buffered 34KB chunk
// staging with counted s_waitcnt vmcnt(N) + raw s_barrier (next-chunk
// loads stay in flight across the barrier); T5 setprio around MFMAs.
__global__ __launch_bounds__(512, 4) void k_main(
    const unsigned short* __restrict__ capT,
    const unsigned short* __restrict__ imgT, const float* __restrict__ G2,
    const int* __restrict__ lens, float* __restrict__ out) {
  __shared__ __align__(16) char lds[LDS_BYTES];
  int tid = threadIdx.x;
  int w = tid >> 6, lane = tid & 63;
  int wc = w >> 2, wi = w & 3;
  int rq = lane & 15, kg = lane >> 4;
  int bid = blockIdx.x;
  int b = (bid & 7) * 64 + (bid >> 3);  // XCD swizzle (512 % 8 == 0)
  int cg = b >> 4, ig = b & 15;
  int c0 = cg * 2, i0 = ig * 4;

  f32x4 acc[4][3];
#pragma unroll
  for (int m = 0; m < 4; ++m)
#pragma unroll
    for (int n = 0; n < 3; ++n) acc[m][n] = 0.f;

  stage_chunk(capT, imgT, lds, c0, i0, 0, w, lane);
#pragma unroll
  for (int ch = 0; ch < 8; ++ch) {
    char* cur = lds + (ch & 1) * CHUNK_BYTES;
    if (ch < 7) {
      stage_chunk(capT, imgT, lds + ((ch + 1) & 1) * CHUNK_BYTES, c0, i0,
                  ch + 1, w, lane);
      // wait only for THIS wave's chunk-ch loads; chunk ch+1 stays in flight
      if (w < 2)
        asm volatile("s_waitcnt vmcnt(5)" ::: "memory");
      else
        asm volatile("s_waitcnt vmcnt(4)" ::: "memory");
    } else {
      asm volatile("s_waitcnt vmcnt(0)" ::: "memory");
    }
    __builtin_amdgcn_s_barrier();  // all waves' chunk-ch loads done
    __builtin_amdgcn_sched_barrier(0);
    __builtin_amdgcn_s_setprio(1);
#pragma unroll
    for (int kk = 0; kk < 2; ++kk) {
      bf16x8 a0 = *(const bf16x8*)(cur + (wc * 8 + 0 * 2 + kk) * 1024 + lane * 16);
      bf16x8 a1 = *(const bf16x8*)(cur + (wc * 8 + 1 * 2 + kk) * 1024 + lane * 16);
      bf16x8 a2 = *(const bf16x8*)(cur + (wc * 8 + 2 * 2 + kk) * 1024 + lane * 16);
      bf16x8 a3 = *(const bf16x8*)(cur + (wc * 8 + 3 * 2 + kk) * 1024 + lane * 16);
      bf16x8 b0 = *(const bf16x8*)(cur + 16384 + ((kk * 4 + wi) * 2 + 0) * 1024 + lane * 16);
      bf16x8 b1 = *(const bf16x8*)(cur + 16384 + ((kk * 4 + wi) * 2 + 1) * 1024 + lane * 16);
      // quarter frag: cols 32..35; lanes rq>=4 read duplicate data whose
      // MFMA output cols (36..47) are never stored -> no masking needed.
      bf16x8 b2 = *(const bf16x8*)(cur + 32768 + kk * 1024 + wi * 256 +
                                   (kg * 4 + (rq & 3)) * 16);

      acc[0][0] = __builtin_amdgcn_mfma_f32_16x16x32_bf16(a0, b0, acc[0][0], 0, 0, 0);
      acc[0][1] = __builtin_amdgcn_mfma_f32_16x16x32_bf16(a0, b1, acc[0][1], 0, 0, 0);
      acc[0][2] = __builtin_amdgcn_mfma_f32_16x16x32_bf16(a0, b2, acc[0][2], 0, 0, 0);
      acc[1][0] = __builtin_amdgcn_mfma_f32_16x16x32_bf16(a1, b0, acc[1][0], 0, 0, 0);
      acc[1][1] = __builtin_amdgcn_mfma_f32_16x16x32_bf16(a1, b1, acc[1][1], 0, 0, 0);
      acc[1][2] = __builtin_amdgcn_mfma_f32_16x16x32_bf16(a1, b2, acc[1][2], 0, 0, 0);
      acc[2][0] = __builtin_amdgcn_mfma_f32_16x16x32_bf16(a2, b0, acc[2][0], 0, 0, 0);
      acc[2][1] = __builtin_amdgcn_mfma_f32_16x16x32_bf16(a2, b1, acc[2][1], 0, 0, 0);
      acc[2][2] = __builtin_amdgcn_mfma_f32_16x16x32_bf16(a2, b2, acc[2][2], 0, 0, 0);
      acc[3][0] = __builtin_amdgcn_mfma_f32_16x16x32_bf16(a3, b0, acc[3][0], 0, 0, 0);
      acc[3][1] = __builtin_amdgcn_mfma_f32_16x16x32_bf16(a3, b1, acc[3][1], 0, 0, 0);
      acc[3][2] = __builtin_amdgcn_mfma_f32_16x16x32_bf16(a3, b2, acc[3][2], 0, 0, 0);
    }
    __builtin_amdgcn_s_setprio(0);
    __builtin_amdgcn_sched_barrier(0);
    __builtin_amdgcn_s_barrier();  // all waves done reading buf before restage
  }

  // S exchange (overlays staging). D layout: col = lane&15, row=(lane>>4)*4+j.
  float* Sf = (float*)lds;
#pragma unroll
  for (int m = 0; m < 4; ++m)
#pragma unroll
    for (int n = 0; n < 3; ++n)
#pragma unroll
      for (int j = 0; j < 4; ++j)
        if (n < 2 || rq < 4)
          Sf[(w * 64 + m * 16 + kg * 4 + j) * SSTR + n * 16 + rq] =
              acc[m][n][j];
  __syncthreads();

  // Epilogue: thread = (pair w, token lane)
  int c = c0 + (w >> 2);
  int i = i0 + (w & 3);
  const float* Srow = Sf + (size_t)(w * 64 + lane) * SSTR;
  float s[36];
#pragma unroll
  for (int r2 = 0; r2 < 18; ++r2) {
    float2 x = *(const float2*)(Srow + r2 * 2);
    s[r2 * 2 + 0] = x.x;
    s[r2 * 2 + 1] = x.y;
  }
  float mx = s[0];
#pragma unroll
  for (int r = 1; r < 36; ++r) mx = fmaxf(mx, s[r]);
  float p[36];
  float sum = 0.f, dotp = 0.f;
#pragma unroll
  for (int r = 0; r < 36; ++r) {
    p[r] = __expf(LAM * (s[r] - mx));
    sum += p[r];
    dotp = fmaf(p[r], s[r], dotp);
  }
  // q2 = p^T G p via triangular loop (G2 has off-diag pre-doubled)
  int iu = __builtin_amdgcn_readfirstlane(i);
  const float* Gi = G2 + (size_t)iu * 1296;
  float q2 = 0.f;
#pragma unroll
  for (int r2 = 0; r2 < 36; ++r2) {
    float t = 0.f;
#pragma unroll
    for (int r = 0; r <= r2; ++r) t = fmaf(Gi[r2 * 36 + r], p[r], t);
    q2 = fmaf(t, p[r2], q2);
  }
  float inv = 1.0f / sum;
  float dn = dotp * inv;
  float nb = sqrtf(fmaxf(q2, 0.f)) * inv;
  float rcos = dn / fmaxf(nb, 1e-8f);
  int len = lens[c];
  float val = (lane < len) ? rcos : 0.f;
#pragma unroll
  for (int off = 1; off < 64; off <<= 1) val += __shfl_xor(val, off);
  if (lane == 0) out[c * 64 + i] = val * (1.0f / 64.0f);
}

extern "C" void kernel_launch(void* const* d_in, const int* in_sizes, int n_in,
                              void* d_out, int out_size, void* d_ws,
                              size_t ws_size, hipStream_t stream) {
  const float* images = (const float*)d_in[0];    // (64,36,512) f32
  const float* captions = (const float*)d_in[1];  // (64,64,512) f32
  const int* lens = (const int*)d_in[2];          // (64,)
  float* out = (float*)d_out;                     // (64,64) f32

  char* ws = (char*)d_ws;
  unsigned short* capT = (unsigned short*)ws;              // 4096*512*2 = 4 MB
  unsigned short* imgT = (unsigned short*)(ws + 4194304);  // 64*18432*2
  float* G = (float*)(ws + 4194304 + 2359296);             // 64*1296*4

  k_prep<<<1664, 256, 0, stream>>>(captions, images, capT, imgT, G);
  k_main<<<512, 512, 0, stream>>>(capT, imgT, G, lens, out);
}